// Round 2
// baseline (424.628 us; speedup 1.0000x reference)
//
#include <hip/hip_runtime.h>
#include <math.h>

// Factorization-machine forward pass, sparsity-aware.
// Every output term is LINEAR in the entries of x (including sum_b_sq), so
// entries with x[i]==0.0f contribute exactly 0 — skipping them is exact for
// any finite weights. Test input has 66 nonzeros out of 2M.
//
//   N = 1,000,000 (u_V: N x 64), M = 500,000 (t_V, b_V: M x 64)
//   P = N + 2M = 2,000,000 = len(x) = len(w_bias), K = 64, GAMMA = (1,1,1,1)
#define N_U 1000000
#define M_T 500000
#define KDIM 64

// Workspace layout (floats):
//   ws[0]        bias accumulator  (dot(x, w_bias))
//   ws[1]        sum_b_sq accumulator
//   ws[8..71]    u_vec, ws[72..135] t_vec, ws[136..199] sum_b
//   ws[248]      (as int) block-arrival counter for last-block finalize
#define WS_BIAS 0
#define WS_SBSQ 1
#define WS_U 8
#define WS_T 72
#define WS_B 136
#define WS_DONE 248
#define WS_FLOATS 256

#define SCAN_BLOCKS 256
#define SCAN_THREADS 256
#define VEC_PER_THREAD 8  // 256*256*8 float4 = 2,097,152 slots >= 500,000

__global__ void init_ws_kernel(float* __restrict__ ws) {
    int i = threadIdx.x;
    if (i < WS_FLOATS) ws[i] = 0.0f;  // bit pattern 0 also zeroes the int counter
}

// Coherent (device-scope) read of a float written by other-XCD atomics.
__device__ __forceinline__ float coherent_read(float* p) {
    return atomicAdd(p, 0.0f);
}

__global__ void __launch_bounds__(SCAN_THREADS)
scan_finalize_kernel(const float* __restrict__ x,
                     const float* __restrict__ w_bias,
                     const float* __restrict__ u_V,
                     const float* __restrict__ t_V,
                     const float* __restrict__ b_V,
                     const float* __restrict__ w0,
                     const float* __restrict__ delta,
                     float* __restrict__ ws,
                     float* __restrict__ out,
                     int P) {
    const int gid = blockIdx.x * blockDim.x + threadIdx.x;
    const int nthreads = SCAN_BLOCKS * SCAN_THREADS;
    const int nvec = (P + 3) / 4;  // 500,000 float4 slots

    // ---- phase 1: scan x, accumulate contributions of nonzeros ----
#pragma unroll
    for (int it = 0; it < VEC_PER_THREAD; ++it) {
        int slot = gid + it * nthreads;
        if (slot >= nvec) break;
        long long base = (long long)slot * 4;
        float4 v = *reinterpret_cast<const float4*>(x + base);
        float vals[4] = {v.x, v.y, v.z, v.w};
#pragma unroll
        for (int j = 0; j < 4; ++j) {
            long long i = base + j;
            if (i >= P) break;
            float xv = vals[j];
            if (xv != 0.0f) {
                atomicAdd(&ws[WS_BIAS], xv * w_bias[i]);
                const float* row;
                float* acc;
                bool is_b = false;
                if (i < N_U) {
                    row = u_V + i * KDIM;
                    acc = ws + WS_U;
                } else if (i < (long long)N_U + M_T) {
                    row = t_V + (i - N_U) * KDIM;
                    acc = ws + WS_T;
                } else {
                    row = b_V + (i - N_U - M_T) * KDIM;
                    acc = ws + WS_B;
                    is_b = true;
                }
                float nrm = 0.0f;
#pragma unroll
                for (int k = 0; k < KDIM; ++k) {
                    float rv = row[k];
                    atomicAdd(&acc[k], xv * rv);
                    nrm += rv * rv;
                }
                if (is_b) atomicAdd(&ws[WS_SBSQ], xv * nrm);
            }
        }
    }

    // ---- phase 2: last-arriving block finalizes ----
    __shared__ int is_last;
    __syncthreads();
    if (threadIdx.x == 0) {
        __threadfence();  // make this block's atomics globally visible (release)
        int old = atomicAdd((int*)(ws + WS_DONE), 1);
        is_last = (old == SCAN_BLOCKS - 1) ? 1 : 0;
    }
    __syncthreads();
    if (!is_last || threadIdx.x >= 64) return;

    __threadfence();  // acquire side
    int k = threadIdx.x;
    // device-scope reads: other XCDs' atomic results must not be served stale
    float u = coherent_read(ws + WS_U + k);
    float t = coherent_read(ws + WS_T + k);
    float b = coherent_read(ws + WS_B + k);

    float ut = u * t;  // dot(u_vec, t_vec)
    float tb = t * b;  // dot(t_vec, sum_b)
    float bb = b * b;  // dot(sum_b, sum_b)
    float ub = u * b;  // dot(u_vec, sum_b)
#pragma unroll
    for (int off = 32; off > 0; off >>= 1) {
        ut += __shfl_down(ut, off);
        tb += __shfl_down(tb, off);
        bb += __shfl_down(bb, off);
        ub += __shfl_down(ub, off);
    }

    if (k == 0) {
        float bias = coherent_read(ws + WS_BIAS);
        float sbsq = coherent_read(ws + WS_SBSQ);
        float bs = 0.5f * (bb - sbsq);
        float y = w0[0] + bias + ut + tb + bs + ub;  // GAMMA = (1,1,1,1)
        float z = y * delta[0];
        out[0] = 1.0f / (1.0f + expf(-z));
    }
}

extern "C" void kernel_launch(void* const* d_in, const int* in_sizes, int n_in,
                              void* d_out, int out_size, void* d_ws, size_t ws_size,
                              hipStream_t stream) {
    // setup_inputs() order: x, delta, pmi, w_0, w_bias, u_V, t_V, b_V
    const float* x      = (const float*)d_in[0];
    const float* delta  = (const float*)d_in[1];
    // d_in[2] = pmi (unused by reference)
    const float* w0     = (const float*)d_in[3];
    const float* w_bias = (const float*)d_in[4];
    const float* u_V    = (const float*)d_in[5];
    const float* t_V    = (const float*)d_in[6];
    const float* b_V    = (const float*)d_in[7];
    float* out = (float*)d_out;
    float* ws  = (float*)d_ws;

    int P = in_sizes[0];  // 2,000,000

    hipLaunchKernelGGL(init_ws_kernel, dim3(1), dim3(256), 0, stream, ws);
    hipLaunchKernelGGL(scan_finalize_kernel, dim3(SCAN_BLOCKS), dim3(SCAN_THREADS),
                       0, stream, x, w_bias, u_V, t_V, b_V, w0, delta, ws, out, P);
}